// Round 4
// baseline (3423.499 us; speedup 1.0000x reference)
//
#include <hip/hip_runtime.h>
#include <float.h>
#include <math.h>

// ============================================================================
// BeamSearchDecoder — MI355X. Greedy-equivalence: h0 = repeat(enc_h,K) and
// scores0 = 0 make all K=3 beams identical; the 9 candidates per batch are
// [v0,v1,v2]x3 and top-3 = three copies of v0 regardless of tie-break, so
// every beam takes the argmax token forever. decoded = one-hot(greedy seq),
// h = final greedy h x3, scores = cumulative (max - logsumexp) x3.
//
// All logits math fp32 (argmax decisions must track the fp32 numpy ref).
//
// R4 vs R3 (2669 us): (a) hipMemsetAsync(135MB) showed 528MB WRITE_SIZE (4x
// amplification, 80 us) -> replaced by k_out writing the whole output with
// float4 stores (one-hot composed inline). (b) k_gemv: 1 col/thread x 32 row
// accs, grid (125, nkc) = 2x waves/SIMD, h via wave-uniform scalar loads
// (no LDS). (c) combine/gru unchanged.
// ============================================================================

#define BB 32
#define HH 512
#define EE 256
#define VV 32000
#define TSTEPS 32
#define NCHK 32                              // combine chunks per row
#define DEC_ELEMS (BB * (TSTEPS + 1) * VV)   // 33,792,000
#define H_ELEMS (BB * 3 * HH)                // 49,152

// ---------------------------------------------------------------------------
// Setup: tiled transpose W_out (V,H) -> Wt_out (H,V)
// ---------------------------------------------------------------------------
__global__ __launch_bounds__(256) void k_transpose_out(
    const float* __restrict__ W, float* __restrict__ Wt) {
  __shared__ float t[32][33];
  const int vb = blockIdx.x * 32;  // 1000
  const int kb = blockIdx.y * 32;  // 16
  const int c = threadIdx.x & 31, rq = threadIdx.x >> 5;
#pragma unroll
  for (int i = 0; i < 4; ++i) {
    int r = rq + i * 8;
    t[r][c] = W[(size_t)(vb + r) * HH + kb + c];
  }
  __syncthreads();
#pragma unroll
  for (int i = 0; i < 4; ++i) {
    int r = rq + i * 8;
    Wt[(size_t)(kb + r) * VV + vb + c] = t[c][r];
  }
}

// ---------------------------------------------------------------------------
// Setup: h0 = encoder_hidden, scores = 0, seq col 0 = START(=1)
// ---------------------------------------------------------------------------
__global__ __launch_bounds__(256) void k_init(
    const float* __restrict__ enc_h, float* __restrict__ hb0,
    float* __restrict__ scores, int* __restrict__ tok_seq) {
  int idx = blockIdx.x * 256 + threadIdx.x;  // 64*256
  if (idx < BB * HH) hb0[idx] = enc_h[idx];
  if (idx < BB) { scores[idx] = 0.0f; tok_seq[idx] = 1; }
}

// ---------------------------------------------------------------------------
// Split-K logits GEMV. Grid (125 vb, nkc kc). Block 256 thr.
// Thread: one vocab col v, 32 row accumulators over KLEN k's.
// h[r][k] access is block-uniform -> scalar (SGPR) loads, no LDS.
// Writes fp32 partials lpart[kc][row][v].
// ---------------------------------------------------------------------------
template <int KLEN>
__global__ __launch_bounds__(256) void k_gemv(
    const float* __restrict__ Wt,    // (H, V)
    const float* __restrict__ hmat,  // (B, H)
    float* __restrict__ lpart) {     // (nkc, B, V)
  const int v = blockIdx.x * 256 + threadIdx.x;  // < 32000
  const int kc = blockIdx.y;
  const int k0 = kc * KLEN;

  float acc[32];
#pragma unroll
  for (int r = 0; r < 32; ++r) acc[r] = 0.0f;

  const float* wp = Wt + (size_t)k0 * VV + v;
  const float* hp = hmat + k0;
#pragma unroll 2
  for (int k = 0; k < KLEN; k += 8) {
    float w[8];
#pragma unroll
    for (int kk = 0; kk < 8; ++kk) w[kk] = wp[(size_t)kk * VV];
    wp += (size_t)8 * VV;
#pragma unroll
    for (int r = 0; r < 32; ++r) {
      const float* hr = hp + r * HH + k;  // block-uniform -> s_load
#pragma unroll
      for (int kk = 0; kk < 8; ++kk) acc[r] = fmaf(hr[kk], w[kk], acc[r]);
    }
  }

  float* lp = lpart + (size_t)kc * BB * VV + v;
#pragma unroll
  for (int r = 0; r < 32; ++r) lp[(size_t)r * VV] = acc[r];
}

// ---------------------------------------------------------------------------
// Combine: logits = sum_kc lpart + bias; per (row, chunk-of-1024) emit
// max / argmax (lowest idx) / sum exp(l - max).
// Grid (NCHK, 32 rows). Block 256 thr; thread = 4 cols (float4).
// ---------------------------------------------------------------------------
__global__ __launch_bounds__(256) void k_combine(
    const float* __restrict__ lpart, const float* __restrict__ bout,
    float* __restrict__ pm, float* __restrict__ ps, int* __restrict__ pidx,
    const int nkc) {
  const int tid = threadIdx.x;
  const int cx = blockIdx.x;   // 0..31
  const int row = blockIdx.y;  // 0..31
  const int c0 = cx * 1024 + tid * 4;
  const bool act = (c0 < VV);

  float l[4];
  float tm = -FLT_MAX; int ti = 0x7fffffff;
  if (act) {
    const float4 b4 = *(const float4*)(bout + c0);
    l[0] = b4.x; l[1] = b4.y; l[2] = b4.z; l[3] = b4.w;
    for (int kc = 0; kc < nkc; ++kc) {
      const float4 p4 = *(const float4*)(lpart + ((size_t)kc * BB + row) * VV + c0);
      l[0] += p4.x; l[1] += p4.y; l[2] += p4.z; l[3] += p4.w;
    }
#pragma unroll
    for (int i = 0; i < 4; ++i) {
      if (l[i] > tm) { tm = l[i]; ti = c0 + i; }
    }
  }
#pragma unroll
  for (int off = 1; off < 64; off <<= 1) {
    const float om = __shfl_xor(tm, off);
    const int oi = __shfl_xor(ti, off);
    if (om > tm || (om == tm && oi < ti)) { tm = om; ti = oi; }
  }
  __shared__ float wm[4]; __shared__ int wi[4];
  __shared__ float bm_s; __shared__ int bi_s;
  __shared__ float wsum[4];
  const int wv = tid >> 6, lane = tid & 63;
  if (lane == 0) { wm[wv] = tm; wi[wv] = ti; }
  __syncthreads();
  if (tid == 0) {
    float m = wm[0]; int ii = wi[0];
#pragma unroll
    for (int w = 1; w < 4; ++w) {
      if (wm[w] > m || (wm[w] == m && wi[w] < ii)) { m = wm[w]; ii = wi[w]; }
    }
    bm_s = m; bi_s = ii;
  }
  __syncthreads();
  const float bm = bm_s;
  float sv = 0.0f;
  if (act) {
#pragma unroll
    for (int i = 0; i < 4; ++i) sv += __expf(l[i] - bm);
  }
#pragma unroll
  for (int off = 1; off < 64; off <<= 1) sv += __shfl_xor(sv, off);
  if (lane == 0) wsum[wv] = sv;
  __syncthreads();
  if (tid == 0) {
    pm[row * NCHK + cx] = bm;
    ps[row * NCHK + cx] = wsum[0] + wsum[1] + wsum[2] + wsum[3];
    pidx[row * NCHK + cx] = bi_s;
  }
}

// ---------------------------------------------------------------------------
// GRU step with fused token-select prologue. Grid 128 = (rg 0..7 of 4 rows) x
// (jt 0..15 of 32 H-cols). Block 256 thr. Native-layout W reads.
// step==TSTEPS: select only.
// ---------------------------------------------------------------------------
__global__ __launch_bounds__(256) void k_gru(
    const int step,
    const float* __restrict__ emb,
    const float* __restrict__ W_ih,   // (1536, 256) native
    const float* __restrict__ W_hh,   // (1536, 512) native
    const float* __restrict__ b_ih, const float* __restrict__ b_hh,
    const float* __restrict__ hin, float* __restrict__ hout,
    const float* __restrict__ pm, const float* __restrict__ ps,
    const int* __restrict__ pidx,
    float* __restrict__ scores, int* __restrict__ tok_seq) {
  const int tid = threadIdx.x;
  const int rg = blockIdx.x >> 4;   // 0..7
  const int jt = blockIdx.x & 15;   // 0..15
  const int r0 = rg * 4, j0 = jt * 32;
  const int lane = tid & 63, wv = tid >> 6;  // wv 0..3

  __shared__ int toks[4];
  __shared__ float xs[4][EE];
  __shared__ float hsm[4][HH];
  __shared__ float gpart[24 * 272];

  // ---- select ----
  if (step == 0) {
    if (tid < 4) toks[tid] = 1;  // START
  } else {
    const int row = r0 + wv;
    const bool cv = (lane < NCHK);
    float m = cv ? pm[row * NCHK + lane] : -FLT_MAX;
    float s = cv ? ps[row * NCHK + lane] : 0.0f;
    int ix = cv ? pidx[row * NCHK + lane] : 0x7fffffff;
    float gm = m; int gi = ix;
#pragma unroll
    for (int off = 1; off < 64; off <<= 1) {
      float om = __shfl_xor(gm, off);
      int oi = __shfl_xor(gi, off);
      if (om > gm || (om == gm && oi < gi)) { gm = om; gi = oi; }
    }
    float term = cv ? s * __expf(m - gm) : 0.0f;
#pragma unroll
    for (int off = 1; off < 64; off <<= 1) term += __shfl_xor(term, off);
    if (lane == 0) {
      toks[wv] = gi;
      if (jt == 0) {
        scores[row] -= logf(term);      // += max - logsumexp
        tok_seq[step * BB + row] = gi;  // seq column `step`
      }
    }
  }
  __syncthreads();
  if (step == TSTEPS) return;

  // ---- stage x = relu(emb[tok]) and h_prev ----
  for (int i = tid; i < 4 * EE; i += 256) {
    const int r = i >> 8, c = i & (EE - 1);
    const float e = emb[(size_t)toks[r] * EE + c];
    xs[r][c] = e > 0.0f ? e : 0.0f;
  }
  for (int i = tid; i < 4 * HH; i += 256) {
    const int r = i >> 9, c = i & (HH - 1);
    hsm[r][c] = hin[(r0 + r) * HH + c];
  }
  __syncthreads();

  const int jh = tid & 31, kq = tid >> 5;  // 32 cols x 8 k-slices
  const int j = j0 + jh;
  float ai[3][4], ah[3][4];
#pragma unroll
  for (int g = 0; g < 3; ++g)
#pragma unroll
    for (int r = 0; r < 4; ++r) { ai[g][r] = 0.0f; ah[g][r] = 0.0f; }

#pragma unroll 2
  for (int q = 0; q < 8; ++q) {
    const int k4 = kq * 32 + q * 4;
    float4 xr[4];
#pragma unroll
    for (int r = 0; r < 4; ++r) xr[r] = *(const float4*)&xs[r][k4];
#pragma unroll
    for (int g = 0; g < 3; ++g) {
      const float4 w = *(const float4*)&W_ih[(size_t)(g * HH + j) * EE + k4];
#pragma unroll
      for (int r = 0; r < 4; ++r) {
        ai[g][r] = fmaf(xr[r].x, w.x, ai[g][r]);
        ai[g][r] = fmaf(xr[r].y, w.y, ai[g][r]);
        ai[g][r] = fmaf(xr[r].z, w.z, ai[g][r]);
        ai[g][r] = fmaf(xr[r].w, w.w, ai[g][r]);
      }
    }
  }
#pragma unroll 2
  for (int q = 0; q < 16; ++q) {
    const int k4 = kq * 64 + q * 4;
    float4 hr[4];
#pragma unroll
    for (int r = 0; r < 4; ++r) hr[r] = *(const float4*)&hsm[r][k4];
#pragma unroll
    for (int g = 0; g < 3; ++g) {
      const float4 w = *(const float4*)&W_hh[(size_t)(g * HH + j) * HH + k4];
#pragma unroll
      for (int r = 0; r < 4; ++r) {
        ah[g][r] = fmaf(hr[r].x, w.x, ah[g][r]);
        ah[g][r] = fmaf(hr[r].y, w.y, ah[g][r]);
        ah[g][r] = fmaf(hr[r].z, w.z, ah[g][r]);
        ah[g][r] = fmaf(hr[r].w, w.w, ah[g][r]);
      }
    }
  }
  {
    const int base = kq * 34 + jh;
#pragma unroll
    for (int g = 0; g < 3; ++g)
#pragma unroll
      for (int r = 0; r < 4; ++r) {
        gpart[(g * 4 + r) * 272 + base] = ai[g][r];
        gpart[(12 + g * 4 + r) * 272 + base] = ah[g][r];
      }
  }
  __syncthreads();

  if (tid < 128) {
    const int r = tid >> 5, jh2 = tid & 31;
    const int j2 = j0 + jh2;
    float g6[6];
#pragma unroll
    for (int c = 0; c < 6; ++c) {
      const int cc = (c < 3) ? (c * 4 + r) : (12 + (c - 3) * 4 + r);
      float s = 0.0f;
#pragma unroll
      for (int q = 0; q < 8; ++q) s += gpart[cc * 272 + q * 34 + jh2];
      g6[c] = s;
    }
    const float ir = g6[0] + b_ih[j2];
    const float iz = g6[1] + b_ih[HH + j2];
    const float in_ = g6[2] + b_ih[2 * HH + j2];
    const float hr_ = g6[3] + b_hh[j2];
    const float hz = g6[4] + b_hh[HH + j2];
    const float hn = g6[5] + b_hh[2 * HH + j2];
    const float rr = 1.0f / (1.0f + expf(-(ir + hr_)));
    const float zz = 1.0f / (1.0f + expf(-(iz + hz)));
    const float nn = tanhf(in_ + rr * hn);
    hout[(r0 + r) * HH + j2] = (1.0f - zz) * nn + zz * hsm[r][j2];
  }
}

// ---------------------------------------------------------------------------
// Full-output writer: one-hot rows composed inline (no memset), h x3,
// scores x3. Grid: 1056 row blocks + 12 h blocks + 1 score block = 1069.
// All stores are float4, full-line, coalesced.
// ---------------------------------------------------------------------------
__global__ __launch_bounds__(256) void k_out(
    const int* __restrict__ tok_seq, const float* __restrict__ hfin,
    const float* __restrict__ scores, float* __restrict__ out) {
  const int blk = blockIdx.x, tid = threadIdx.x;
  if (blk < BB * (TSTEPS + 1)) {           // one (b,t) one-hot row
    const int b = blk / (TSTEPS + 1), t = blk % (TSTEPS + 1);
    const int tok = tok_seq[t * BB + b];
    const int tq = tok >> 2, tl = tok & 3;
    float4* op = (float4*)(out + (size_t)blk * VV);
    for (int i = tid; i < VV / 4; i += 256) {
      float4 z = {0.0f, 0.0f, 0.0f, 0.0f};
      if (i == tq) (&z.x)[tl] = 1.0f;
      op[i] = z;
    }
  } else if (blk < BB * (TSTEPS + 1) + 12) {  // h x3: 12288 float4
    const int i4 = (blk - BB * (TSTEPS + 1)) * 1024 + tid;
    // 12288 float4 total; blocks of 1024 f4, 256 thr x 4 iters
    for (int i = i4; i < i4 + 1; ++i) {}  // (single index per thread below)
#pragma unroll
    for (int it = 0; it < 4; ++it) {
      const int idx = (blk - BB * (TSTEPS + 1)) * 1024 + it * 256 + tid;
      if (idx < H_ELEMS / 4) {
        const int fi = idx * 4;
        const int b = fi / (3 * HH);
        const int j0 = (fi % (3 * HH)) % HH;
        ((float4*)(out + DEC_ELEMS))[idx] =
            *(const float4*)(hfin + b * HH + j0);
      }
    }
  } else {                                   // scores x3: 96 floats
    if (tid < BB * 3) {
      out[(size_t)DEC_ELEMS + H_ELEMS + tid] = scores[tid / 3];
    }
  }
}

// ---------------------------------------------------------------------------
extern "C" void kernel_launch(void* const* d_in, const int* in_sizes, int n_in,
                              void* d_out, int out_size, void* d_ws, size_t ws_size,
                              hipStream_t stream) {
  const float* enc_h = (const float*)d_in[1];
  const float* emb   = (const float*)d_in[2];
  const float* W_ih  = (const float*)d_in[3];
  const float* W_hh  = (const float*)d_in[4];
  const float* b_ih  = (const float*)d_in[5];
  const float* b_hh  = (const float*)d_in[6];
  const float* W_out = (const float*)d_in[7];
  const float* b_out = (const float*)d_in[8];
  float* out = (float*)d_out;

  // workspace layout (floats)
  float* ws = (float*)d_ws;
  float* Wt_out  = ws;                       // 16,384,000
  float* hb0     = Wt_out + 16384000;        // 16,384
  float* hb1     = hb0 + BB * HH;            // 16,384
  float* pm      = hb1 + BB * HH;            // 1,024
  float* ps      = pm + BB * NCHK;           // 1,024
  float* scores  = ps + BB * NCHK;           // 32
  int*   pidx    = (int*)(scores + BB);      // 1,024
  int*   tok_seq = pidx + BB * NCHK;         // 1,056
  float* lpart   = (float*)(tok_seq + BB * (TSTEPS + 1));  // nkc*32*32000

  const size_t fixed = 16384000 + 2 * BB * HH + 2 * BB * NCHK + BB +
                       BB * NCHK + BB * (TSTEPS + 1);
  int nkc = 4;
  if (ws_size < (fixed + 4ull * BB * VV) * 4) nkc = 2;
  if (ws_size < (fixed + 2ull * BB * VV) * 4) nkc = 1;

  k_transpose_out<<<dim3(1000, 16), 256, 0, stream>>>(W_out, Wt_out);
  k_init<<<64, 256, 0, stream>>>(enc_h, hb0, scores, tok_seq);

  for (int t = 0; t < TSTEPS; ++t) {
    float* hin  = (t & 1) ? hb1 : hb0;
    float* hout = (t & 1) ? hb0 : hb1;
    k_gru<<<128, 256, 0, stream>>>(t, emb, W_ih, W_hh, b_ih, b_hh,
                                   hin, hout, pm, ps, pidx, scores, tok_seq);
    if (nkc == 4)
      k_gemv<128><<<dim3(125, 4), 256, 0, stream>>>(Wt_out, hout, lpart);
    else if (nkc == 2)
      k_gemv<256><<<dim3(125, 2), 256, 0, stream>>>(Wt_out, hout, lpart);
    else
      k_gemv<512><<<dim3(125, 1), 256, 0, stream>>>(Wt_out, hout, lpart);
    k_combine<<<dim3(NCHK, BB), 256, 0, stream>>>(lpart, b_out, pm, ps, pidx, nkc);
  }
  // final selection: seq col 32 + last score term
  k_gru<<<128, 256, 0, stream>>>(TSTEPS, emb, W_ih, W_hh, b_ih, b_hh,
                                 hb0, hb1, pm, ps, pidx, scores, tok_seq);
  // final h lives in hb0 (t=31 odd: hout=hb0); full-output writer
  k_out<<<BB * (TSTEPS + 1) + 13, 256, 0, stream>>>(tok_seq, hb0, scores, out);
}

// Round 5
// 2143.849 us; speedup vs baseline: 1.5969x; 1.5969x over previous
//
#include <hip/hip_runtime.h>
#include <float.h>
#include <math.h>

// ============================================================================
// BeamSearchDecoder — MI355X. Greedy-equivalence: h0 = repeat(enc_h,K) and
// scores0 = 0 make all K=3 beams identical; the 9 candidates per batch are
// [v0,v1,v2]x3 and top-3 = three copies of v0 regardless of tie-break, so
// every beam takes the argmax token forever. decoded = one-hot(greedy seq),
// h = final greedy h x3, scores = cumulative (max - logsumexp) x3.
//
// All logits math fp32 (argmax decisions must track the fp32 numpy ref).
//
// R5 vs R4 (3423 us): R4's k_gemv h-feed ("uniform -> s_load") actually
// lowered to per-lane VMEM + addr calc (VALUBusy 35% = 4x FMA need, 82 us).
// Now h chunk staged in LDS, inner loop reads wave-uniform float4 ->
// ds_read_b128 broadcast. 1024 DS : 4096 FMA insts per thread.
// ============================================================================

#define BB 32
#define HH 512
#define EE 256
#define VV 32000
#define TSTEPS 32
#define NCHK 32                              // combine chunks per row
#define DEC_ELEMS (BB * (TSTEPS + 1) * VV)   // 33,792,000
#define H_ELEMS (BB * 3 * HH)                // 49,152

// ---------------------------------------------------------------------------
// Setup: tiled transpose W_out (V,H) -> Wt_out (H,V)
// ---------------------------------------------------------------------------
__global__ __launch_bounds__(256) void k_transpose_out(
    const float* __restrict__ W, float* __restrict__ Wt) {
  __shared__ float t[32][33];
  const int vb = blockIdx.x * 32;  // 1000
  const int kb = blockIdx.y * 32;  // 16
  const int c = threadIdx.x & 31, rq = threadIdx.x >> 5;
#pragma unroll
  for (int i = 0; i < 4; ++i) {
    int r = rq + i * 8;
    t[r][c] = W[(size_t)(vb + r) * HH + kb + c];
  }
  __syncthreads();
#pragma unroll
  for (int i = 0; i < 4; ++i) {
    int r = rq + i * 8;
    Wt[(size_t)(kb + r) * VV + vb + c] = t[c][r];
  }
}

// ---------------------------------------------------------------------------
// Setup: h0 = encoder_hidden, scores = 0, seq col 0 = START(=1)
// ---------------------------------------------------------------------------
__global__ __launch_bounds__(256) void k_init(
    const float* __restrict__ enc_h, float* __restrict__ hb0,
    float* __restrict__ scores, int* __restrict__ tok_seq) {
  int idx = blockIdx.x * 256 + threadIdx.x;  // 64*256
  if (idx < BB * HH) hb0[idx] = enc_h[idx];
  if (idx < BB) { scores[idx] = 0.0f; tok_seq[idx] = 1; }
}

// ---------------------------------------------------------------------------
// Split-K logits GEMV. Grid (125 vb, nkc kc). Block 256 thr.
// Thread: one vocab col v = vb*256+tid, 32 row accumulators over KLEN k's.
// h chunk (32 x KLEN = 16 KB @KLEN=128) staged in LDS; inner reads are
// wave-uniform float4 -> ds_read_b128 broadcast (conflict-free, cheap).
// Writes fp32 partials lpart[kc][row][v].
// ---------------------------------------------------------------------------
template <int KLEN>
__global__ __launch_bounds__(256) void k_gemv(
    const float* __restrict__ Wt,    // (H, V)
    const float* __restrict__ hmat,  // (B, H)
    float* __restrict__ lpart) {     // (nkc, B, V)
  __shared__ float hs[32 * KLEN];
  const int tid = threadIdx.x;
  const int kc = blockIdx.y;
  const int k0 = kc * KLEN;

  // stage h chunk: hs[r][k'] = hmat[r*HH + k0 + k']
  {
    constexpr int KQ4 = KLEN / 4;               // float4 per row
    float4* hd = (float4*)hs;
    const float4* hp = (const float4*)hmat;
    for (int i = tid; i < 32 * KQ4; i += 256) {
      const int r = i / KQ4, off = i % KQ4;     // KQ4 is pow2 -> shifts
      hd[i] = hp[r * (HH / 4) + (k0 / 4) + off];
    }
  }
  __syncthreads();

  const int v = blockIdx.x * 256 + tid;  // 125*256 = 32000, exact
  float acc[32];
#pragma unroll
  for (int r = 0; r < 32; ++r) acc[r] = 0.0f;

  const float* wp = Wt + (size_t)k0 * VV + v;
#pragma unroll 2
  for (int kb = 0; kb < KLEN; kb += 4) {
    float w0 = wp[0];
    float w1 = wp[(size_t)VV];
    float w2 = wp[(size_t)2 * VV];
    float w3 = wp[(size_t)3 * VV];
    wp += (size_t)4 * VV;
#pragma unroll
    for (int r = 0; r < 32; ++r) {
      const float4 h4 = *(const float4*)&hs[r * KLEN + kb];  // broadcast
      acc[r] = fmaf(h4.x, w0, acc[r]);
      acc[r] = fmaf(h4.y, w1, acc[r]);
      acc[r] = fmaf(h4.z, w2, acc[r]);
      acc[r] = fmaf(h4.w, w3, acc[r]);
    }
  }

  float* lp = lpart + (size_t)kc * BB * VV + v;
#pragma unroll
  for (int r = 0; r < 32; ++r) lp[(size_t)r * VV] = acc[r];
}

// ---------------------------------------------------------------------------
// Combine: logits = sum_kc lpart + bias; per (row, chunk-of-1024) emit
// max / argmax (lowest idx) / sum exp(l - max).
// Grid (NCHK, 32 rows). Block 256 thr; thread = 4 cols (float4).
// ---------------------------------------------------------------------------
__global__ __launch_bounds__(256) void k_combine(
    const float* __restrict__ lpart, const float* __restrict__ bout,
    float* __restrict__ pm, float* __restrict__ ps, int* __restrict__ pidx,
    const int nkc) {
  const int tid = threadIdx.x;
  const int cx = blockIdx.x;   // 0..31
  const int row = blockIdx.y;  // 0..31
  const int c0 = cx * 1024 + tid * 4;
  const bool act = (c0 < VV);

  float l[4];
  float tm = -FLT_MAX; int ti = 0x7fffffff;
  if (act) {
    const float4 b4 = *(const float4*)(bout + c0);
    l[0] = b4.x; l[1] = b4.y; l[2] = b4.z; l[3] = b4.w;
    for (int kc = 0; kc < nkc; ++kc) {
      const float4 p4 = *(const float4*)(lpart + ((size_t)kc * BB + row) * VV + c0);
      l[0] += p4.x; l[1] += p4.y; l[2] += p4.z; l[3] += p4.w;
    }
#pragma unroll
    for (int i = 0; i < 4; ++i) {
      if (l[i] > tm) { tm = l[i]; ti = c0 + i; }
    }
  }
#pragma unroll
  for (int off = 1; off < 64; off <<= 1) {
    const float om = __shfl_xor(tm, off);
    const int oi = __shfl_xor(ti, off);
    if (om > tm || (om == tm && oi < ti)) { tm = om; ti = oi; }
  }
  __shared__ float wm[4]; __shared__ int wi[4];
  __shared__ float bm_s; __shared__ int bi_s;
  __shared__ float wsum[4];
  const int wv = tid >> 6, lane = tid & 63;
  if (lane == 0) { wm[wv] = tm; wi[wv] = ti; }
  __syncthreads();
  if (tid == 0) {
    float m = wm[0]; int ii = wi[0];
#pragma unroll
    for (int w = 1; w < 4; ++w) {
      if (wm[w] > m || (wm[w] == m && wi[w] < ii)) { m = wm[w]; ii = wi[w]; }
    }
    bm_s = m; bi_s = ii;
  }
  __syncthreads();
  const float bm = bm_s;
  float sv = 0.0f;
  if (act) {
#pragma unroll
    for (int i = 0; i < 4; ++i) sv += __expf(l[i] - bm);
  }
#pragma unroll
  for (int off = 1; off < 64; off <<= 1) sv += __shfl_xor(sv, off);
  if (lane == 0) wsum[wv] = sv;
  __syncthreads();
  if (tid == 0) {
    pm[row * NCHK + cx] = bm;
    ps[row * NCHK + cx] = wsum[0] + wsum[1] + wsum[2] + wsum[3];
    pidx[row * NCHK + cx] = bi_s;
  }
}

// ---------------------------------------------------------------------------
// GRU step with fused token-select prologue. Grid 128 = (rg 0..7 of 4 rows) x
// (jt 0..15 of 32 H-cols). Block 256 thr. Native-layout W reads.
// step==TSTEPS: select only.
// ---------------------------------------------------------------------------
__global__ __launch_bounds__(256) void k_gru(
    const int step,
    const float* __restrict__ emb,
    const float* __restrict__ W_ih,   // (1536, 256) native
    const float* __restrict__ W_hh,   // (1536, 512) native
    const float* __restrict__ b_ih, const float* __restrict__ b_hh,
    const float* __restrict__ hin, float* __restrict__ hout,
    const float* __restrict__ pm, const float* __restrict__ ps,
    const int* __restrict__ pidx,
    float* __restrict__ scores, int* __restrict__ tok_seq) {
  const int tid = threadIdx.x;
  const int rg = blockIdx.x >> 4;   // 0..7
  const int jt = blockIdx.x & 15;   // 0..15
  const int r0 = rg * 4, j0 = jt * 32;
  const int lane = tid & 63, wv = tid >> 6;  // wv 0..3

  __shared__ int toks[4];
  __shared__ float xs[4][EE];
  __shared__ float hsm[4][HH];
  __shared__ float gpart[24 * 272];

  // ---- select ----
  if (step == 0) {
    if (tid < 4) toks[tid] = 1;  // START
  } else {
    const int row = r0 + wv;
    const bool cv = (lane < NCHK);
    float m = cv ? pm[row * NCHK + lane] : -FLT_MAX;
    float s = cv ? ps[row * NCHK + lane] : 0.0f;
    int ix = cv ? pidx[row * NCHK + lane] : 0x7fffffff;
    float gm = m; int gi = ix;
#pragma unroll
    for (int off = 1; off < 64; off <<= 1) {
      float om = __shfl_xor(gm, off);
      int oi = __shfl_xor(gi, off);
      if (om > gm || (om == gm && oi < gi)) { gm = om; gi = oi; }
    }
    float term = cv ? s * __expf(m - gm) : 0.0f;
#pragma unroll
    for (int off = 1; off < 64; off <<= 1) term += __shfl_xor(term, off);
    if (lane == 0) {
      toks[wv] = gi;
      if (jt == 0) {
        scores[row] -= logf(term);      // += max - logsumexp
        tok_seq[step * BB + row] = gi;  // seq column `step`
      }
    }
  }
  __syncthreads();
  if (step == TSTEPS) return;

  // ---- stage x = relu(emb[tok]) and h_prev ----
  for (int i = tid; i < 4 * EE; i += 256) {
    const int r = i >> 8, c = i & (EE - 1);
    const float e = emb[(size_t)toks[r] * EE + c];
    xs[r][c] = e > 0.0f ? e : 0.0f;
  }
  for (int i = tid; i < 4 * HH; i += 256) {
    const int r = i >> 9, c = i & (HH - 1);
    hsm[r][c] = hin[(r0 + r) * HH + c];
  }
  __syncthreads();

  const int jh = tid & 31, kq = tid >> 5;  // 32 cols x 8 k-slices
  const int j = j0 + jh;
  float ai[3][4], ah[3][4];
#pragma unroll
  for (int g = 0; g < 3; ++g)
#pragma unroll
    for (int r = 0; r < 4; ++r) { ai[g][r] = 0.0f; ah[g][r] = 0.0f; }

#pragma unroll 2
  for (int q = 0; q < 8; ++q) {
    const int k4 = kq * 32 + q * 4;
    float4 xr[4];
#pragma unroll
    for (int r = 0; r < 4; ++r) xr[r] = *(const float4*)&xs[r][k4];
#pragma unroll
    for (int g = 0; g < 3; ++g) {
      const float4 w = *(const float4*)&W_ih[(size_t)(g * HH + j) * EE + k4];
#pragma unroll
      for (int r = 0; r < 4; ++r) {
        ai[g][r] = fmaf(xr[r].x, w.x, ai[g][r]);
        ai[g][r] = fmaf(xr[r].y, w.y, ai[g][r]);
        ai[g][r] = fmaf(xr[r].z, w.z, ai[g][r]);
        ai[g][r] = fmaf(xr[r].w, w.w, ai[g][r]);
      }
    }
  }
#pragma unroll 2
  for (int q = 0; q < 16; ++q) {
    const int k4 = kq * 64 + q * 4;
    float4 hr[4];
#pragma unroll
    for (int r = 0; r < 4; ++r) hr[r] = *(const float4*)&hsm[r][k4];
#pragma unroll
    for (int g = 0; g < 3; ++g) {
      const float4 w = *(const float4*)&W_hh[(size_t)(g * HH + j) * HH + k4];
#pragma unroll
      for (int r = 0; r < 4; ++r) {
        ah[g][r] = fmaf(hr[r].x, w.x, ah[g][r]);
        ah[g][r] = fmaf(hr[r].y, w.y, ah[g][r]);
        ah[g][r] = fmaf(hr[r].z, w.z, ah[g][r]);
        ah[g][r] = fmaf(hr[r].w, w.w, ah[g][r]);
      }
    }
  }
  {
    const int base = kq * 34 + jh;
#pragma unroll
    for (int g = 0; g < 3; ++g)
#pragma unroll
      for (int r = 0; r < 4; ++r) {
        gpart[(g * 4 + r) * 272 + base] = ai[g][r];
        gpart[(12 + g * 4 + r) * 272 + base] = ah[g][r];
      }
  }
  __syncthreads();

  if (tid < 128) {
    const int r = tid >> 5, jh2 = tid & 31;
    const int j2 = j0 + jh2;
    float g6[6];
#pragma unroll
    for (int c = 0; c < 6; ++c) {
      const int cc = (c < 3) ? (c * 4 + r) : (12 + (c - 3) * 4 + r);
      float s = 0.0f;
#pragma unroll
      for (int q = 0; q < 8; ++q) s += gpart[cc * 272 + q * 34 + jh2];
      g6[c] = s;
    }
    const float ir = g6[0] + b_ih[j2];
    const float iz = g6[1] + b_ih[HH + j2];
    const float in_ = g6[2] + b_ih[2 * HH + j2];
    const float hr_ = g6[3] + b_hh[j2];
    const float hz = g6[4] + b_hh[HH + j2];
    const float hn = g6[5] + b_hh[2 * HH + j2];
    const float rr = 1.0f / (1.0f + expf(-(ir + hr_)));
    const float zz = 1.0f / (1.0f + expf(-(iz + hz)));
    const float nn = tanhf(in_ + rr * hn);
    hout[(r0 + r) * HH + j2] = (1.0f - zz) * nn + zz * hsm[r][j2];
  }
}

// ---------------------------------------------------------------------------
// Full-output writer: one-hot rows composed inline (no memset), h x3,
// scores x3. All stores float4, coalesced.
// ---------------------------------------------------------------------------
__global__ __launch_bounds__(256) void k_out(
    const int* __restrict__ tok_seq, const float* __restrict__ hfin,
    const float* __restrict__ scores, float* __restrict__ out) {
  const int blk = blockIdx.x, tid = threadIdx.x;
  if (blk < BB * (TSTEPS + 1)) {           // one (b,t) one-hot row
    const int b = blk / (TSTEPS + 1), t = blk % (TSTEPS + 1);
    const int tok = tok_seq[t * BB + b];
    const int tq = tok >> 2, tl = tok & 3;
    float4* op = (float4*)(out + (size_t)blk * VV);
    for (int i = tid; i < VV / 4; i += 256) {
      float4 z = {0.0f, 0.0f, 0.0f, 0.0f};
      if (i == tq) (&z.x)[tl] = 1.0f;
      op[i] = z;
    }
  } else if (blk < BB * (TSTEPS + 1) + 12) {  // h x3: 12288 float4
#pragma unroll
    for (int it = 0; it < 4; ++it) {
      const int idx = (blk - BB * (TSTEPS + 1)) * 1024 + it * 256 + tid;
      if (idx < H_ELEMS / 4) {
        const int fi = idx * 4;
        const int b = fi / (3 * HH);
        const int j0 = (fi % (3 * HH)) % HH;
        ((float4*)(out + DEC_ELEMS))[idx] =
            *(const float4*)(hfin + b * HH + j0);
      }
    }
  } else {                                   // scores x3: 96 floats
    if (tid < BB * 3) {
      out[(size_t)DEC_ELEMS + H_ELEMS + tid] = scores[tid / 3];
    }
  }
}

// ---------------------------------------------------------------------------
extern "C" void kernel_launch(void* const* d_in, const int* in_sizes, int n_in,
                              void* d_out, int out_size, void* d_ws, size_t ws_size,
                              hipStream_t stream) {
  const float* enc_h = (const float*)d_in[1];
  const float* emb   = (const float*)d_in[2];
  const float* W_ih  = (const float*)d_in[3];
  const float* W_hh  = (const float*)d_in[4];
  const float* b_ih  = (const float*)d_in[5];
  const float* b_hh  = (const float*)d_in[6];
  const float* W_out = (const float*)d_in[7];
  const float* b_out = (const float*)d_in[8];
  float* out = (float*)d_out;

  // workspace layout (floats)
  float* ws = (float*)d_ws;
  float* Wt_out  = ws;                       // 16,384,000
  float* hb0     = Wt_out + 16384000;        // 16,384
  float* hb1     = hb0 + BB * HH;            // 16,384
  float* pm      = hb1 + BB * HH;            // 1,024
  float* ps      = pm + BB * NCHK;           // 1,024
  float* scores  = ps + BB * NCHK;           // 32
  int*   pidx    = (int*)(scores + BB);      // 1,024
  int*   tok_seq = pidx + BB * NCHK;         // 1,056
  float* lpart   = (float*)(tok_seq + BB * (TSTEPS + 1));  // nkc*32*32000

  const size_t fixed = 16384000 + 2 * BB * HH + 2 * BB * NCHK + BB +
                       BB * NCHK + BB * (TSTEPS + 1);
  int nkc = 4;                               // R4 profile confirms nkc=4 fits
  if (ws_size < (fixed + 4ull * BB * VV) * 4) nkc = 2;
  if (ws_size < (fixed + 2ull * BB * VV) * 4) nkc = 1;

  k_transpose_out<<<dim3(1000, 16), 256, 0, stream>>>(W_out, Wt_out);
  k_init<<<64, 256, 0, stream>>>(enc_h, hb0, scores, tok_seq);

  for (int t = 0; t < TSTEPS; ++t) {
    float* hin  = (t & 1) ? hb1 : hb0;
    float* hout = (t & 1) ? hb0 : hb1;
    k_gru<<<128, 256, 0, stream>>>(t, emb, W_ih, W_hh, b_ih, b_hh,
                                   hin, hout, pm, ps, pidx, scores, tok_seq);
    if (nkc == 4)
      k_gemv<128><<<dim3(125, 4), 256, 0, stream>>>(Wt_out, hout, lpart);
    else if (nkc == 2)
      k_gemv<256><<<dim3(125, 2), 256, 0, stream>>>(Wt_out, hout, lpart);
    else
      k_gemv<512><<<dim3(125, 1), 256, 0, stream>>>(Wt_out, hout, lpart);
    k_combine<<<dim3(NCHK, BB), 256, 0, stream>>>(lpart, b_out, pm, ps, pidx, nkc);
  }
  // final selection: seq col 32 + last score term
  k_gru<<<128, 256, 0, stream>>>(TSTEPS, emb, W_ih, W_hh, b_ih, b_hh,
                                 hb0, hb1, pm, ps, pidx, scores, tok_seq);
  // final h lives in hb0 (t=31 odd: hout=hb0); full-output writer
  k_out<<<BB * (TSTEPS + 1) + 13, 256, 0, stream>>>(tok_seq, hb0, scores, out);
}